// Round 2
// baseline (883.494 us; speedup 1.0000x reference)
//
#include <hip/hip_runtime.h>
#include <stdint.h>

// Problem constants
#define B_   4
#define P_   20000
#define NB_  9
#define WN_  17
#define CI_  64
#define CO_  128
#define PTS  32            // points per block -> 4 waves, each = 1 batch row x 32 points x CO=128
#define NBLK (P_ / PTS)    // 625 blocks

#define NCH     9          // B-panel chunks per pass: 8 chunks of 2 m + 1 tail chunk of 1 m
#define CHBYTES 16384      // full chunk = 2 m * 4 oloc * 128 co * 16B

typedef __fp16 f16x8 __attribute__((ext_vector_type(8)));
typedef __fp16 h2    __attribute__((ext_vector_type(2)));
typedef float  f32x16 __attribute__((ext_vector_type(16)));

union H2U { h2 h; uint32_t u; };
union F8U { f16x8 v; h2 h[4]; uint4 u; };

// async global->LDS, 16B per lane, wave-uniform LDS base (HW adds lane*16)
__device__ __forceinline__ void gload_lds16(const void* g, void* l) {
    __builtin_amdgcn_global_load_lds(
        (const __attribute__((address_space(1))) uint32_t*)g,
        (__attribute__((address_space(3))) uint32_t*)l, 16, 0, 0);
}

// wsb granule (16B = 8 f16) index: (((m*2+pass)*4 + oloc)*128 + co)*8 ushorts.
__global__ void prep_wm(const float* __restrict__ w, ushort* __restrict__ wsb) {
    int i = blockIdx.x * 256 + threadIdx.x;     // 0 .. 17407 (17*2*4*128)
    int m2p  = i >> 9;                          // m*2+pass
    int r    = i & 511;
    int oloc = r >> 7, co = r & 127;
    int m = m2p >> 1, p = m2p & 1;
    const float* src = w + (size_t)m * (CO_ * CI_) + co * CI_ + (p * 4 + oloc) * 8;
    float4 v0 = *(const float4*)(src);
    float4 v1 = *(const float4*)(src + 4);
    F8U h;
    h.h[0] = __builtin_amdgcn_cvt_pkrtz(v0.x, v0.y);
    h.h[1] = __builtin_amdgcn_cvt_pkrtz(v0.z, v0.w);
    h.h[2] = __builtin_amdgcn_cvt_pkrtz(v1.x, v1.y);
    h.h[3] = __builtin_amdgcn_cvt_pkrtz(v1.z, v1.w);
    *(uint4*)&wsb[(size_t)((m2p * 4 + oloc) * 128 + co) * 8] = h.u;
}

template <bool PRE>
__global__ __launch_bounds__(256, 3)
void lasm_fused(const float* __restrict__ in_pc,    // (B,P,CI)    f32
                const float* __restrict__ raw_w,    // (P,NB,WN)   f32
                const float* __restrict__ weights,  // (WN,CO*CI)  f32
                const float* __restrict__ bias,     // (P,CO)      f32
                const int*   __restrict__ nbr,      // (P,NB)      int32
                const ushort* __restrict__ wsb,     // pre-swizzled f16 panel
                float*       __restrict__ out)      // (B,P,CO)    f32
{
    // chunk layout: granule (m2, oloc, co) at byte (m2*512 + oloc*128 + co)*16
    __shared__ __align__(1024) unsigned char s_buf[2 * CHBYTES];   // 32 KB double buffer
    // stride-33 pad: staging writes (bank step 9) and 32-lane reads both conflict-free
    __shared__ __align__(16) uint32_t s_w2[WN_ * NB_ * 33];        // ~20.2 KB
    // total 52.96 KB -> 3 blocks/CU

    const int tid  = threadIdx.x;
    const int lane = tid & 63;
    const int wv   = tid >> 6;        // batch row 0..3 (one wave per batch)
    const int arow = lane & 31;       // point-local index / A-row / co within co-tile
    const int q    = lane >> 5;       // k-half
    const int p0   = blockIdx.x * PTS;

    const size_t binpc = (size_t)wv * P_ * CI_;

    h2 x[NB_][8];
    auto gather = [&](int pass) {
        const int ch0 = pass * 32 + q * 8;
        #pragma unroll
        for (int n = 0; n < NB_; ++n) {
            uint32_t nid = (uint32_t)nbr[(size_t)(p0 + arow) * NB_ + n];
            if (nid < (uint32_t)P_) {
                const float* src = in_pc + binpc + (size_t)nid * CI_ + ch0;
                float4 a0 = *(const float4*)(src);
                float4 a1 = *(const float4*)(src + 4);
                float4 b0 = *(const float4*)(src + 16);
                float4 b1 = *(const float4*)(src + 20);
                x[n][0] = __builtin_amdgcn_cvt_pkrtz(a0.x, a0.y);
                x[n][1] = __builtin_amdgcn_cvt_pkrtz(a0.z, a0.w);
                x[n][2] = __builtin_amdgcn_cvt_pkrtz(a1.x, a1.y);
                x[n][3] = __builtin_amdgcn_cvt_pkrtz(a1.z, a1.w);
                x[n][4] = __builtin_amdgcn_cvt_pkrtz(b0.x, b0.y);
                x[n][5] = __builtin_amdgcn_cvt_pkrtz(b0.z, b0.w);
                x[n][6] = __builtin_amdgcn_cvt_pkrtz(b1.x, b1.y);
                x[n][7] = __builtin_amdgcn_cvt_pkrtz(b1.z, b1.w);
            } else {
                h2 z = {(__fp16)0.f, (__fp16)0.f};
                #pragma unroll
                for (int j = 0; j < 8; ++j) x[n][j] = z;
            }
        }
    };

    // cooperative async stage of B-panel chunk g into buf[g&1]
    auto issue_chunk = [&](int g) {
        if (g >= 2 * NCH) return;
        const int pass = (g >= NCH) ? 1 : 0;
        const int cc   = g - pass * NCH;
        const int m0   = cc * 2;
        const int mcnt = (cc == NCH - 1) ? 1 : 2;
        const int ipw  = mcnt * 2;                    // 16B wave-issues per wave
        const uint lb  = (uint)(g & 1) * CHBYTES;
        for (int i = 0; i < ipw; ++i) {
            const int wi = wv * ipw + i;              // wave-issue index in chunk
            const int gi = wi * 64 + lane;            // granule index in chunk
            const int m  = m0 + (gi >> 9);
            const int r  = gi & 511;                  // oloc*128 + co
            if (PRE) {
                const ushort* src = wsb + (size_t)((m * 2 + pass) * 512 + r) * 8;
                gload_lds16(src, s_buf + lb + (uint)wi * 1024u);
            } else {
                const int oloc = r >> 7, co = r & 127;
                const float* s = weights + (size_t)m * (CO_ * CI_)
                               + co * CI_ + (pass * 4 + oloc) * 8;
                float4 v0 = *(const float4*)(s);
                float4 v1 = *(const float4*)(s + 4);
                F8U h;
                h.h[0] = __builtin_amdgcn_cvt_pkrtz(v0.x, v0.y);
                h.h[1] = __builtin_amdgcn_cvt_pkrtz(v0.z, v0.w);
                h.h[2] = __builtin_amdgcn_cvt_pkrtz(v1.x, v1.y);
                h.h[3] = __builtin_amdgcn_cvt_pkrtz(v1.z, v1.w);
                *(uint4*)(s_buf + lb + (uint)gi * 16u) = h.u;
            }
        }
    };

    f32x16 acc[4];
    #pragma unroll
    for (int c = 0; c < 4; ++c)
        #pragma unroll
        for (int j = 0; j < 16; ++j) acc[c][j] = 0.f;

    auto compute_m = [&](uint lb, int m2, int m, bool regather) {
        H2U wc[NB_];
        #pragma unroll
        for (int n = 0; n < NB_; ++n) wc[n].u = s_w2[(m * NB_ + n) * 33 + arow];

        // B fragments from LDS (consecutive-16B per lane -> conflict-free b128)
        const uint fb = lb + (uint)(m2 * 8192 + q * 2048 + arow * 16);
        F8U bf0[4], bf1[4];
        #pragma unroll
        for (int c = 0; c < 4; ++c)
            bf0[c].u = *(const uint4*)(s_buf + fb + c * 512);
        #pragma unroll
        for (int c = 0; c < 4; ++c)
            bf1[c].u = *(const uint4*)(s_buf + fb + 4096 + c * 512);

        // stage-1 in registers
        F8U f[2];
        #pragma unroll
        for (int kk = 0; kk < 2; ++kk)
            #pragma unroll
            for (int r4 = 0; r4 < 4; ++r4) {
                h2 c2 = {(__fp16)0.f, (__fp16)0.f};
                #pragma unroll
                for (int n = 0; n < NB_; ++n) c2 += wc[n].h * x[n][kk * 4 + r4];
                f[kk].h[r4] = c2;
            }

        if (regather) gather(1);   // x dead for pass 0 here; latency hides under MFMAs

        #pragma unroll
        for (int c = 0; c < 4; ++c)
            acc[c] = __builtin_amdgcn_mfma_f32_32x32x16_f16(f[0].v, bf0[c].v, acc[c], 0, 0, 0);
        #pragma unroll
        for (int c = 0; c < 4; ++c)
            acc[c] = __builtin_amdgcn_mfma_f32_32x32x16_f16(f[1].v, bf1[c].v, acc[c], 0, 0, 0);
    };

    // ---- prologue: gathers + chunk0 fly while s_w2 stages ----
    gather(0);
    issue_chunk(0);
    for (int idx = tid; idx < PTS * NB_ * WN_; idx += 256) {
        int pl2 = idx / (NB_ * WN_);
        int rem = idx % (NB_ * WN_);
        int n   = rem / WN_;
        int m   = rem % WN_;
        float wf = raw_w[(size_t)p0 * NB_ * WN_ + idx];
        H2U c; c.h = __builtin_amdgcn_cvt_pkrtz(wf, wf);
        s_w2[(m * NB_ + n) * 33 + pl2] = c.u;
    }
    __syncthreads();

    // ---- double-buffered chunk loop (18 chunks, 1 barrier each) ----
    for (int g = 0; g < 2 * NCH; ++g) {
        issue_chunk(g + 1);                         // prefetch next chunk
        const int cc = (g >= NCH) ? g - NCH : g;
        const uint lb = (uint)(g & 1) * CHBYTES;
        if (cc < NCH - 1) {
            compute_m(lb, 0, cc * 2, false);
            compute_m(lb, 1, cc * 2 + 1, false);
        } else {
            compute_m(lb, 0, 2 * (NCH - 1), g == NCH - 1);  // regather after pass-0 tail
        }
        __syncthreads();                            // drains prefetch, guards buffer reuse
    }

    // ---- epilogue: bias + ELU + nontemporal fp32 store ----
    #pragma unroll
    for (int c = 0; c < 4; ++c) {
        int col = c * 32 + arow;
        #pragma unroll
        for (int v = 0; v < 16; ++v) {
            int lr = (v & 3) + 8 * (v >> 2) + 4 * q;   // local row 0..31 in M-tile
            int p  = p0 + lr;
            float val = acc[c][v] + bias[(size_t)p * CO_ + col];
            val = (val > 0.f) ? val : (__expf(val) - 1.f);
            __builtin_nontemporal_store(val, &out[((size_t)wv * P_ + p) * CO_ + col]);
        }
    }
}

extern "C" void kernel_launch(void* const* d_in, const int* in_sizes, int n_in,
                              void* d_out, int out_size, void* d_ws, size_t ws_size,
                              hipStream_t stream) {
    const float* in_pc   = (const float*)d_in[0];
    const float* raw_w   = (const float*)d_in[1];
    const float* weights = (const float*)d_in[2];
    const float* bias    = (const float*)d_in[3];
    const int*   nbr     = (const int*)  d_in[4];
    float* out = (float*)d_out;

    const size_t need = (size_t)WN_ * 2 * 4096 * sizeof(ushort);   // 278,528 B
    if (d_ws != nullptr && ws_size >= need) {
        ushort* wsb = (ushort*)d_ws;
        prep_wm<<<dim3(WN_ * 2 * 512 / 256), dim3(256), 0, stream>>>(weights, wsb);
        lasm_fused<true><<<dim3(NBLK), dim3(256), 0, stream>>>(
            in_pc, raw_w, weights, bias, nbr, wsb, out);
    } else {
        lasm_fused<false><<<dim3(NBLK), dim3(256), 0, stream>>>(
            in_pc, raw_w, weights, bias, nbr, nullptr, out);
    }
}

// Round 3
// 292.895 us; speedup vs baseline: 3.0164x; 3.0164x over previous
//
#include <hip/hip_runtime.h>
#include <stdint.h>

// Problem constants
#define B_   4
#define P_   20000
#define NB_  9
#define WN_  17
#define CI_  64
#define CO_  128
#define PTS  32            // points per block -> 4 waves, each = 1 batch row x 32 points x CO=128
#define NBLK (P_ / PTS)    // 625 blocks

#define NCH     9          // B-panel chunks per pass: 8 chunks of 2 m + 1 tail chunk of 1 m
#define CHBYTES 16384      // full chunk = 2 m * 4 oloc * 128 co * 16B

typedef __fp16 f16x8 __attribute__((ext_vector_type(8)));
typedef __fp16 h2    __attribute__((ext_vector_type(2)));
typedef float  f32x16 __attribute__((ext_vector_type(16)));

union H2U { h2 h; uint32_t u; };
union F8U { f16x8 v; h2 h[4]; uint4 u; };

// async global->LDS, 16B per lane, wave-uniform LDS base (HW adds lane*16)
__device__ __forceinline__ void gload_lds16(const void* g, void* l) {
    __builtin_amdgcn_global_load_lds(
        (const __attribute__((address_space(1))) uint32_t*)g,
        (__attribute__((address_space(3))) uint32_t*)l, 16, 0, 0);
}

// wsb granule (16B = 8 f16) index: (((m*2+pass)*4 + oloc)*128 + co)*8 ushorts.
__global__ void prep_wm(const float* __restrict__ w, ushort* __restrict__ wsb) {
    int i = blockIdx.x * 256 + threadIdx.x;     // 0 .. 17407 (17*2*4*128)
    int m2p  = i >> 9;                          // m*2+pass
    int r    = i & 511;
    int oloc = r >> 7, co = r & 127;
    int m = m2p >> 1, p = m2p & 1;
    const float* src = w + (size_t)m * (CO_ * CI_) + co * CI_ + (p * 4 + oloc) * 8;
    float4 v0 = *(const float4*)(src);
    float4 v1 = *(const float4*)(src + 4);
    F8U h;
    h.h[0] = __builtin_amdgcn_cvt_pkrtz(v0.x, v0.y);
    h.h[1] = __builtin_amdgcn_cvt_pkrtz(v0.z, v0.w);
    h.h[2] = __builtin_amdgcn_cvt_pkrtz(v1.x, v1.y);
    h.h[3] = __builtin_amdgcn_cvt_pkrtz(v1.z, v1.w);
    *(uint4*)&wsb[(size_t)((m2p * 4 + oloc) * 128 + co) * 8] = h.u;
}

// NOTE round-3: launch_bounds min-waves 3 -> 2. Round 2's (256,3) forced a
// ~170-reg budget; the ~200-reg live set (acc 64 AGPR + x 36 + bf 32 + ...)
// spilled x to scratch -> 2.1 GB of HBM writes, 9x regression. Budget 256
// holds everything in regs at the same 8 waves/CU residency as round 1.
template <bool PRE>
__global__ __launch_bounds__(256, 2)
void lasm_fused(const float* __restrict__ in_pc,    // (B,P,CI)    f32
                const float* __restrict__ raw_w,    // (P,NB,WN)   f32
                const float* __restrict__ weights,  // (WN,CO*CI)  f32
                const float* __restrict__ bias,     // (P,CO)      f32
                const int*   __restrict__ nbr,      // (P,NB)      int32
                const ushort* __restrict__ wsb,     // pre-swizzled f16 panel
                float*       __restrict__ out)      // (B,P,CO)    f32
{
    // chunk layout: granule (m2, oloc, co) at byte (m2*512 + oloc*128 + co)*16
    __shared__ __align__(1024) unsigned char s_buf[2 * CHBYTES];   // 32 KB double buffer
    // stride-33 pad: staging writes (bank step 9) and 32-lane reads both conflict-free
    __shared__ __align__(16) uint32_t s_w2[WN_ * NB_ * 33];        // ~20.2 KB

    const int tid  = threadIdx.x;
    const int lane = tid & 63;
    const int wv   = tid >> 6;        // batch row 0..3 (one wave per batch)
    const int arow = lane & 31;       // point-local index / A-row / co within co-tile
    const int q    = lane >> 5;       // k-half
    const int p0   = blockIdx.x * PTS;

    const size_t binpc = (size_t)wv * P_ * CI_;

    h2 x[NB_][8];
    auto gather = [&](int pass) {
        const int ch0 = pass * 32 + q * 8;
        #pragma unroll
        for (int n = 0; n < NB_; ++n) {
            uint32_t nid = (uint32_t)nbr[(size_t)(p0 + arow) * NB_ + n];
            if (nid < (uint32_t)P_) {
                const float* src = in_pc + binpc + (size_t)nid * CI_ + ch0;
                float4 a0 = *(const float4*)(src);
                float4 a1 = *(const float4*)(src + 4);
                float4 b0 = *(const float4*)(src + 16);
                float4 b1 = *(const float4*)(src + 20);
                x[n][0] = __builtin_amdgcn_cvt_pkrtz(a0.x, a0.y);
                x[n][1] = __builtin_amdgcn_cvt_pkrtz(a0.z, a0.w);
                x[n][2] = __builtin_amdgcn_cvt_pkrtz(a1.x, a1.y);
                x[n][3] = __builtin_amdgcn_cvt_pkrtz(a1.z, a1.w);
                x[n][4] = __builtin_amdgcn_cvt_pkrtz(b0.x, b0.y);
                x[n][5] = __builtin_amdgcn_cvt_pkrtz(b0.z, b0.w);
                x[n][6] = __builtin_amdgcn_cvt_pkrtz(b1.x, b1.y);
                x[n][7] = __builtin_amdgcn_cvt_pkrtz(b1.z, b1.w);
            } else {
                h2 z = {(__fp16)0.f, (__fp16)0.f};
                #pragma unroll
                for (int j = 0; j < 8; ++j) x[n][j] = z;
            }
        }
    };

    // cooperative async stage of B-panel chunk g into buf[g&1]
    auto issue_chunk = [&](int g) {
        if (g >= 2 * NCH) return;
        const int pass = (g >= NCH) ? 1 : 0;
        const int cc   = g - pass * NCH;
        const int m0   = cc * 2;
        const int mcnt = (cc == NCH - 1) ? 1 : 2;
        const int ipw  = mcnt * 2;                    // 16B wave-issues per wave
        const uint lb  = (uint)(g & 1) * CHBYTES;
        for (int i = 0; i < ipw; ++i) {
            const int wi = wv * ipw + i;              // wave-issue index in chunk
            const int gi = wi * 64 + lane;            // granule index in chunk
            const int m  = m0 + (gi >> 9);
            const int r  = gi & 511;                  // oloc*128 + co
            if (PRE) {
                const ushort* src = wsb + (size_t)((m * 2 + pass) * 512 + r) * 8;
                gload_lds16(src, s_buf + lb + (uint)wi * 1024u);
            } else {
                const int oloc = r >> 7, co = r & 127;
                const float* s = weights + (size_t)m * (CO_ * CI_)
                               + co * CI_ + (pass * 4 + oloc) * 8;
                float4 v0 = *(const float4*)(s);
                float4 v1 = *(const float4*)(s + 4);
                F8U h;
                h.h[0] = __builtin_amdgcn_cvt_pkrtz(v0.x, v0.y);
                h.h[1] = __builtin_amdgcn_cvt_pkrtz(v0.z, v0.w);
                h.h[2] = __builtin_amdgcn_cvt_pkrtz(v1.x, v1.y);
                h.h[3] = __builtin_amdgcn_cvt_pkrtz(v1.z, v1.w);
                *(uint4*)(s_buf + lb + (uint)gi * 16u) = h.u;
            }
        }
    };

    f32x16 acc[4];
    #pragma unroll
    for (int c = 0; c < 4; ++c)
        #pragma unroll
        for (int j = 0; j < 16; ++j) acc[c][j] = 0.f;

    auto compute_m = [&](uint lb, int m2, int m, bool regather) {
        H2U wc[NB_];
        #pragma unroll
        for (int n = 0; n < NB_; ++n) wc[n].u = s_w2[(m * NB_ + n) * 33 + arow];

        // B fragments from LDS (consecutive-16B per lane -> conflict-free b128)
        const uint fb = lb + (uint)(m2 * 8192 + q * 2048 + arow * 16);
        F8U bf0[4], bf1[4];
        #pragma unroll
        for (int c = 0; c < 4; ++c)
            bf0[c].u = *(const uint4*)(s_buf + fb + c * 512);
        #pragma unroll
        for (int c = 0; c < 4; ++c)
            bf1[c].u = *(const uint4*)(s_buf + fb + 4096 + c * 512);

        // stage-1 in registers
        F8U f[2];
        #pragma unroll
        for (int kk = 0; kk < 2; ++kk)
            #pragma unroll
            for (int r4 = 0; r4 < 4; ++r4) {
                h2 c2 = {(__fp16)0.f, (__fp16)0.f};
                #pragma unroll
                for (int n = 0; n < NB_; ++n) c2 += wc[n].h * x[n][kk * 4 + r4];
                f[kk].h[r4] = c2;
            }

        if (regather) gather(1);   // x dead for pass 0 here; latency hides under MFMAs

        #pragma unroll
        for (int c = 0; c < 4; ++c)
            acc[c] = __builtin_amdgcn_mfma_f32_32x32x16_f16(f[0].v, bf0[c].v, acc[c], 0, 0, 0);
        #pragma unroll
        for (int c = 0; c < 4; ++c)
            acc[c] = __builtin_amdgcn_mfma_f32_32x32x16_f16(f[1].v, bf1[c].v, acc[c], 0, 0, 0);
    };

    // ---- prologue: gathers + chunk0 fly while s_w2 stages ----
    gather(0);
    issue_chunk(0);
    for (int idx = tid; idx < PTS * NB_ * WN_; idx += 256) {
        int pl2 = idx / (NB_ * WN_);
        int rem = idx % (NB_ * WN_);
        int n   = rem / WN_;
        int m   = rem % WN_;
        float wf = raw_w[(size_t)p0 * NB_ * WN_ + idx];
        H2U c; c.h = __builtin_amdgcn_cvt_pkrtz(wf, wf);
        s_w2[(m * NB_ + n) * 33 + pl2] = c.u;
    }
    __syncthreads();

    // ---- double-buffered chunk loop (18 chunks, 1 barrier each) ----
    for (int g = 0; g < 2 * NCH; ++g) {
        issue_chunk(g + 1);                         // prefetch next chunk
        const int cc = (g >= NCH) ? g - NCH : g;
        const uint lb = (uint)(g & 1) * CHBYTES;
        if (cc < NCH - 1) {
            compute_m(lb, 0, cc * 2, false);
            compute_m(lb, 1, cc * 2 + 1, false);
        } else {
            compute_m(lb, 0, 2 * (NCH - 1), g == NCH - 1);  // regather after pass-0 tail
        }
        __syncthreads();                            // drains prefetch, guards buffer reuse
    }

    // ---- epilogue: bias + ELU + nontemporal fp32 store ----
    #pragma unroll
    for (int c = 0; c < 4; ++c) {
        int col = c * 32 + arow;
        #pragma unroll
        for (int v = 0; v < 16; ++v) {
            int lr = (v & 3) + 8 * (v >> 2) + 4 * q;   // local row 0..31 in M-tile
            int p  = p0 + lr;
            float val = acc[c][v] + bias[(size_t)p * CO_ + col];
            val = (val > 0.f) ? val : (__expf(val) - 1.f);
            __builtin_nontemporal_store(val, &out[((size_t)wv * P_ + p) * CO_ + col]);
        }
    }
}

extern "C" void kernel_launch(void* const* d_in, const int* in_sizes, int n_in,
                              void* d_out, int out_size, void* d_ws, size_t ws_size,
                              hipStream_t stream) {
    const float* in_pc   = (const float*)d_in[0];
    const float* raw_w   = (const float*)d_in[1];
    const float* weights = (const float*)d_in[2];
    const float* bias    = (const float*)d_in[3];
    const int*   nbr     = (const int*)  d_in[4];
    float* out = (float*)d_out;

    const size_t need = (size_t)WN_ * 2 * 4096 * sizeof(ushort);   // 278,528 B
    if (d_ws != nullptr && ws_size >= need) {
        ushort* wsb = (ushort*)d_ws;
        prep_wm<<<dim3(WN_ * 2 * 512 / 256), dim3(256), 0, stream>>>(weights, wsb);
        lasm_fused<true><<<dim3(NBLK), dim3(256), 0, stream>>>(
            in_pc, raw_w, weights, bias, nbr, wsb, out);
    } else {
        lasm_fused<false><<<dim3(NBLK), dim3(256), 0, stream>>>(
            in_pc, raw_w, weights, bias, nbr, nullptr, out);
    }
}

// Round 4
// 189.925 us; speedup vs baseline: 4.6518x; 1.5422x over previous
//
#include <hip/hip_runtime.h>
#include <stdint.h>

// Problem constants
#define B_   4
#define P_   20000
#define NB_  9
#define WN_  17
#define CI_  64
#define CO_  128
#define PTS  32            // points per block -> 4 waves, each = 1 batch row x 32 points x CO=128
#define NBLK (P_ / PTS)    // 625 blocks

// Sections: s = pass*2 + kk (4 sections, each K=16 over all 17 m)
#define MCH     4          // m's per full chunk
#define NCH     5          // chunks per section: 4,4,4,4,1
#define CHBYTES 16384      // 4 m * 2 q * 128 co * 16B

typedef __fp16 f16x8 __attribute__((ext_vector_type(8)));
typedef __fp16 h2    __attribute__((ext_vector_type(2)));
typedef float  f32x16 __attribute__((ext_vector_type(16)));

union H2U { h2 h; uint32_t u; };
union F8U { f16x8 v; h2 h[4]; uint4 u; };

// async global->LDS, 16B per lane, wave-uniform LDS base (HW adds lane*16)
__device__ __forceinline__ void gload_lds16(const void* g, void* l) {
    __builtin_amdgcn_global_load_lds(
        (const __attribute__((address_space(1))) uint32_t*)g,
        (__attribute__((address_space(3))) uint32_t*)l, 16, 0, 0);
}

// wsb granule (16B = 8 f16 = 8 consecutive ci) index:
//   G = ((s*WN_ + m)*2 + q)*128 + co,  s = pass*2+kk
// source floats: weights[m][co*CI + s*16 + q*8 .. +7]
__global__ void prep_wm(const float* __restrict__ w, ushort* __restrict__ wsb) {
    int i = blockIdx.x * 256 + threadIdx.x;     // 0 .. 17407
    int co = i & 127;
    int t  = i >> 7;
    int q  = t & 1;  t >>= 1;
    int m  = t % WN_;
    int s  = t / WN_;                            // pass*2 + kk
    const float* src = w + (size_t)m * (CO_ * CI_) + co * CI_ + s * 16 + q * 8;
    float4 v0 = *(const float4*)(src);
    float4 v1 = *(const float4*)(src + 4);
    F8U h;
    h.h[0] = __builtin_amdgcn_cvt_pkrtz(v0.x, v0.y);
    h.h[1] = __builtin_amdgcn_cvt_pkrtz(v0.z, v0.w);
    h.h[2] = __builtin_amdgcn_cvt_pkrtz(v1.x, v1.y);
    h.h[3] = __builtin_amdgcn_cvt_pkrtz(v1.z, v1.w);
    *(uint4*)&wsb[(size_t)i * 8] = h.u;
}

// Round-4: kk-split. Round 3 spilled ~13 regs/iter (WRITE_SIZE 385MB) because
// the live set (x=72 + bf=32 + wc+f + acc 64 AGPR) peaked >256 unified regs.
// Splitting each pass into its two K=16 sub-steps halves x to 36 regs and
// sequencing stage-1-then-MFMA per chunk keeps the peaks from stacking.
template <bool PRE>
__global__ __launch_bounds__(256, 2)
void lasm_fused(const float* __restrict__ in_pc,    // (B,P,CI)    f32
                const float* __restrict__ raw_w,    // (P,NB,WN)   f32
                const float* __restrict__ weights,  // (WN,CO*CI)  f32
                const float* __restrict__ bias,     // (P,CO)      f32
                const int*   __restrict__ nbr,      // (P,NB)      int32
                const ushort* __restrict__ wsb,     // pre-swizzled f16 panel
                float*       __restrict__ out)      // (B,P,CO)    f32
{
    // chunk layout: granule (mm, q, co) at byte ((mm*2+q)*128 + co)*16
    __shared__ __align__(1024) unsigned char s_buf[2 * CHBYTES];   // 32 KB double buffer
    // stride-33 pad: staging writes (bank step 9) and 32-lane reads both conflict-free
    __shared__ __align__(16) uint32_t s_w2[WN_ * NB_ * 33];        // ~20.2 KB

    const int tid  = threadIdx.x;
    const int lane = tid & 63;
    const int wv   = tid >> 6;        // batch row 0..3 (one wave per batch)
    const int arow = lane & 31;       // point-local index / A-row / co within co-tile
    const int q    = lane >> 5;       // k-half within the section's K=16
    const int p0   = blockIdx.x * PTS;

    const size_t binpc = (size_t)wv * P_ * CI_;

    h2 x[NB_][4];                      // 36 VGPRs: this section's 8 ci per lane
    auto gather = [&](int s) {         // s = pass*2 + kk
        const int ch0 = s * 16 + q * 8;
        #pragma unroll
        for (int n = 0; n < NB_; ++n) {
            uint32_t nid = (uint32_t)nbr[(size_t)(p0 + arow) * NB_ + n];
            if (nid < (uint32_t)P_) {
                const float* src = in_pc + binpc + (size_t)nid * CI_ + ch0;
                float4 a0 = *(const float4*)(src);
                float4 a1 = *(const float4*)(src + 4);
                x[n][0] = __builtin_amdgcn_cvt_pkrtz(a0.x, a0.y);
                x[n][1] = __builtin_amdgcn_cvt_pkrtz(a0.z, a0.w);
                x[n][2] = __builtin_amdgcn_cvt_pkrtz(a1.x, a1.y);
                x[n][3] = __builtin_amdgcn_cvt_pkrtz(a1.z, a1.w);
            } else {
                h2 z = {(__fp16)0.f, (__fp16)0.f};
                #pragma unroll
                for (int j = 0; j < 4; ++j) x[n][j] = z;
            }
        }
    };

    // cooperative async stage of chunk g into buf[g&1]; 1 wave-issue per wave per m
    auto issue_chunk = [&](int g) {
        if (g >= 4 * NCH) return;
        const int s    = g / NCH;
        const int cc   = g - s * NCH;
        const int m0   = cc * MCH;
        const int mcnt = (cc == NCH - 1) ? 1 : MCH;
        const uint lb  = (uint)(g & 1) * CHBYTES;
        const int gbase = (s * WN_ + m0) * 256;
        for (int i = 0; i < mcnt; ++i) {
            if (PRE) {
                const ushort* src = wsb + (size_t)(gbase + i * 256 + wv * 64 + lane) * 8;
                gload_lds16(src, s_buf + lb + (uint)(i * 4 + wv) * 1024u);
            } else {
                const int g2 = i * 256 + wv * 64 + lane;
                const int mm = g2 >> 8;
                const int qq = (g2 >> 7) & 1;
                const int co = g2 & 127;
                const float* sp = weights + (size_t)(m0 + mm) * (CO_ * CI_)
                                + co * CI_ + s * 16 + qq * 8;
                float4 v0 = *(const float4*)(sp);
                float4 v1 = *(const float4*)(sp + 4);
                F8U h;
                h.h[0] = __builtin_amdgcn_cvt_pkrtz(v0.x, v0.y);
                h.h[1] = __builtin_amdgcn_cvt_pkrtz(v0.z, v0.w);
                h.h[2] = __builtin_amdgcn_cvt_pkrtz(v1.x, v1.y);
                h.h[3] = __builtin_amdgcn_cvt_pkrtz(v1.z, v1.w);
                *(uint4*)(s_buf + lb + (uint)g2 * 16u) = h.u;
            }
        }
    };

    f32x16 acc[4];
    #pragma unroll
    for (int c = 0; c < 4; ++c)
        #pragma unroll
        for (int j = 0; j < 16; ++j) acc[c][j] = 0.f;

    // stage-1 for one m -> A-fragment (reads x + s_w2 only)
    auto stage1 = [&](int m) -> f16x8 {
        H2U wc[NB_];
        #pragma unroll
        for (int n = 0; n < NB_; ++n) wc[n].u = s_w2[(m * NB_ + n) * 33 + arow];
        F8U fa;
        #pragma unroll
        for (int r4 = 0; r4 < 4; ++r4) {
            h2 c2 = {(__fp16)0.f, (__fp16)0.f};
            #pragma unroll
            for (int n = 0; n < NB_; ++n) c2 += wc[n].h * x[n][r4];
            fa.h[r4] = c2;
        }
        return fa.v;
    };

    // B-frags from LDS (consecutive-16B per lane -> conflict-free b128) + 4 MFMAs
    auto mfma_m = [&](uint lb, int mm, f16x8 fa) {
        const uint fb = lb + (uint)(mm * 4096 + q * 2048 + arow * 16);
        F8U bf[4];
        #pragma unroll
        for (int c = 0; c < 4; ++c)
            bf[c].u = *(const uint4*)(s_buf + fb + c * 512);
        #pragma unroll
        for (int c = 0; c < 4; ++c)
            acc[c] = __builtin_amdgcn_mfma_f32_32x32x16_f16(fa, bf[c].v, acc[c], 0, 0, 0);
    };

    // ---- prologue: gathers + chunk0 fly while s_w2 stages ----
    gather(0);
    issue_chunk(0);
    for (int idx = tid; idx < PTS * NB_ * WN_; idx += 256) {
        int pl2 = idx / (NB_ * WN_);
        int rem = idx % (NB_ * WN_);
        int n   = rem / WN_;
        int m   = rem % WN_;
        float wf = raw_w[(size_t)p0 * NB_ * WN_ + idx];
        H2U c; c.h = __builtin_amdgcn_cvt_pkrtz(wf, wf);
        s_w2[(m * NB_ + n) * 33 + pl2] = c.u;
    }
    __syncthreads();

    // ---- double-buffered chunk loop (20 chunks, 1 barrier each) ----
    f16x8 ftail{};
    for (int g = 0; g < 4 * NCH; ++g) {
        issue_chunk(g + 1);                         // prefetch next chunk
        const int s  = g / NCH;
        const int cc = g - s * NCH;
        const int m0 = cc * MCH;
        const uint lb = (uint)(g & 1) * CHBYTES;
        if (cc < NCH - 1) {
            f16x8 f0 = stage1(m0 + 0);
            f16x8 f1 = stage1(m0 + 1);
            f16x8 f2 = stage1(m0 + 2);
            f16x8 f3 = stage1(m0 + 3);
            if (cc == NCH - 2) {
                ftail = stage1(WN_ - 1);            // tail m's stage-1 early: x dead after
                if (s < 3) gather(s + 1);           // next section's x; hides under MFMAs
            }
            mfma_m(lb, 0, f0);
            mfma_m(lb, 1, f1);
            mfma_m(lb, 2, f2);
            mfma_m(lb, 3, f3);
        } else {
            mfma_m(lb, 0, ftail);                   // B-chunk for m=16 just arrived
        }
        __syncthreads();                            // drains prefetch, guards buffer reuse
    }

    // ---- epilogue: bias + ELU + nontemporal fp32 store ----
    #pragma unroll
    for (int c = 0; c < 4; ++c) {
        int col = c * 32 + arow;
        #pragma unroll
        for (int v = 0; v < 16; ++v) {
            int lr = (v & 3) + 8 * (v >> 2) + 4 * q;   // local row 0..31 in M-tile
            int p  = p0 + lr;
            float val = acc[c][v] + bias[(size_t)p * CO_ + col];
            val = (val > 0.f) ? val : (__expf(val) - 1.f);
            __builtin_nontemporal_store(val, &out[((size_t)wv * P_ + p) * CO_ + col]);
        }
    }
}

extern "C" void kernel_launch(void* const* d_in, const int* in_sizes, int n_in,
                              void* d_out, int out_size, void* d_ws, size_t ws_size,
                              hipStream_t stream) {
    const float* in_pc   = (const float*)d_in[0];
    const float* raw_w   = (const float*)d_in[1];
    const float* weights = (const float*)d_in[2];
    const float* bias    = (const float*)d_in[3];
    const int*   nbr     = (const int*)  d_in[4];
    float* out = (float*)d_out;

    const size_t need = (size_t)4 * WN_ * 2 * 128 * 8 * sizeof(ushort);   // 278,528 B
    if (d_ws != nullptr && ws_size >= need) {
        ushort* wsb = (ushort*)d_ws;
        prep_wm<<<dim3(68), dim3(256), 0, stream>>>(weights, wsb);
        lasm_fused<true><<<dim3(NBLK), dim3(256), 0, stream>>>(
            in_pc, raw_w, weights, bias, nbr, wsb, out);
    } else {
        lasm_fused<false><<<dim3(NBLK), dim3(256), 0, stream>>>(
            in_pc, raw_w, weights, bias, nbr, nullptr, out);
    }
}